// Round 1
// baseline (265.957 us; speedup 1.0000x reference)
//
#include <hip/hip_runtime.h>
#include <hip/hip_bf16.h>
#include <cstdint>
#include <cstddef>

// Problem constants
#define B_   64
#define LC_  1024
#define LQ_  128
#define D_   128

typedef __bf16 bf16;
typedef bf16  bf16x8 __attribute__((ext_vector_type(8)));
typedef bf16  bf16x4 __attribute__((ext_vector_type(4)));
typedef float f32x4  __attribute__((ext_vector_type(4)));

__device__ __forceinline__ f32x4 mfma16(bf16x8 a, bf16x8 b, f32x4 c) {
  return __builtin_amdgcn_mfma_f32_16x16x32_bf16(a, b, c, 0, 0, 0);
}

// ---------------------------------------------------------------------------
// K0c: per (b, 128-row k-slice): cw1[b,k] = c.w1 ; cw3 = bf16(c*w3) ; cT = bf16(c)^T
// ---------------------------------------------------------------------------
__global__ __launch_bounds__(256) void k0c(const float* __restrict__ c, const float* __restrict__ w,
                                           float* __restrict__ cw1, bf16* __restrict__ cw3,
                                           bf16* __restrict__ cT) {
  __shared__ float w1s[128];
  __shared__ float w3s[128];
  __shared__ bf16  ctile[128 * 132];
  const int b = blockIdx.y, ks = blockIdx.x;
  const int k0 = ks * 128;
  const int t = threadIdx.x;
  if (t < 128) { w1s[t] = w[t]; w3s[t] = w[256 + t]; }
  __syncthreads();
  {
    const int r = t >> 1, d0 = (t & 1) * 64;
    const float* crow = c + ((size_t)(b * LC_ + k0 + r) * D_ + d0);
    bf16* orow = cw3 + ((size_t)(b * LC_ + k0 + r) * D_ + d0);
    float dot = 0.f;
#pragma unroll
    for (int v = 0; v < 8; ++v) {
      const float4 f0 = ((const float4*)crow)[v * 2 + 0];
      const float4 f1 = ((const float4*)crow)[v * 2 + 1];
      const int dd = d0 + v * 8;
      dot += f0.x * w1s[dd + 0] + f0.y * w1s[dd + 1] + f0.z * w1s[dd + 2] + f0.w * w1s[dd + 3]
           + f1.x * w1s[dd + 4] + f1.y * w1s[dd + 5] + f1.z * w1s[dd + 6] + f1.w * w1s[dd + 7];
      bf16* cr = &ctile[r * 132 + dd];
      cr[0] = (bf16)f0.x; cr[1] = (bf16)f0.y; cr[2] = (bf16)f0.z; cr[3] = (bf16)f0.w;
      cr[4] = (bf16)f1.x; cr[5] = (bf16)f1.y; cr[6] = (bf16)f1.z; cr[7] = (bf16)f1.w;
      bf16x8 o;
      o[0] = (bf16)(f0.x * w3s[dd + 0]); o[1] = (bf16)(f0.y * w3s[dd + 1]);
      o[2] = (bf16)(f0.z * w3s[dd + 2]); o[3] = (bf16)(f0.w * w3s[dd + 3]);
      o[4] = (bf16)(f1.x * w3s[dd + 4]); o[5] = (bf16)(f1.y * w3s[dd + 5]);
      o[6] = (bf16)(f1.z * w3s[dd + 6]); o[7] = (bf16)(f1.w * w3s[dd + 7]);
      *(bf16x8*)(orow + v * 8) = o;
    }
    dot += __shfl_xor(dot, 1);
    if ((t & 1) == 0) cw1[b * LC_ + k0 + r] = dot;
  }
  __syncthreads();
  {
    const int d = t >> 1, kh = (t & 1) * 64;
    bf16* trow = cT + ((size_t)(b * D_ + d) * LC_ + k0 + kh);
#pragma unroll
    for (int v = 0; v < 8; ++v) {
      bf16x8 o;
#pragma unroll
      for (int e = 0; e < 8; ++e) o[e] = ctile[(kh + v * 8 + e) * 132 + d];
      *(bf16x8*)(trow + v * 8) = o;
    }
  }
}

// ---------------------------------------------------------------------------
// K0q: per batch: qw2[b,j] = q.w2 ; qb = bf16(q) ; qT = bf16(q)^T
// ---------------------------------------------------------------------------
__global__ __launch_bounds__(256) void k0q(const float* __restrict__ q, const float* __restrict__ w,
                                           float* __restrict__ qw2, bf16* __restrict__ qb,
                                           bf16* __restrict__ qT) {
  __shared__ float w2s[128];
  __shared__ bf16  qtile[128 * 132];
  const int b = blockIdx.x;
  const int t = threadIdx.x;
  if (t < 128) w2s[t] = w[128 + t];
  __syncthreads();
  {
    const int r = t >> 1, d0 = (t & 1) * 64;
    const float* qrow = q + ((size_t)(b * LQ_ + r) * D_ + d0);
    bf16* orow = qb + ((size_t)(b * LQ_ + r) * D_ + d0);
    float dot = 0.f;
#pragma unroll
    for (int v = 0; v < 8; ++v) {
      const float4 f0 = ((const float4*)qrow)[v * 2 + 0];
      const float4 f1 = ((const float4*)qrow)[v * 2 + 1];
      const int dd = d0 + v * 8;
      dot += f0.x * w2s[dd + 0] + f0.y * w2s[dd + 1] + f0.z * w2s[dd + 2] + f0.w * w2s[dd + 3]
           + f1.x * w2s[dd + 4] + f1.y * w2s[dd + 5] + f1.z * w2s[dd + 6] + f1.w * w2s[dd + 7];
      bf16x8 o;
      o[0] = (bf16)f0.x; o[1] = (bf16)f0.y; o[2] = (bf16)f0.z; o[3] = (bf16)f0.w;
      o[4] = (bf16)f1.x; o[5] = (bf16)f1.y; o[6] = (bf16)f1.z; o[7] = (bf16)f1.w;
      bf16* qr = &qtile[r * 132 + dd];
#pragma unroll
      for (int e = 0; e < 8; ++e) qr[e] = o[e];
      *(bf16x8*)(orow + v * 8) = o;
    }
    dot += __shfl_xor(dot, 1);
    if ((t & 1) == 0) qw2[b * LQ_ + r] = dot;
  }
  __syncthreads();
  {
    const int d = t >> 1, jh = (t & 1) * 64;
    bf16* trow = qT + ((size_t)(b * D_ + d) * LQ_ + jh);
#pragma unroll
    for (int v = 0; v < 8; ++v) {
      bf16x8 o;
#pragma unroll
      for (int e = 0; e < 8; ++e) o[e] = qtile[(jh + v * 8 + e) * 132 + d];
      *(bf16x8*)(trow + v * 8) = o;
    }
  }
}

// ---------------------------------------------------------------------------
// K1: per (b, 32-wide j-slice): column softmax (mask=c_mask on k) over all k,
//     T[j,d] = sum_k P[k,j] c[k,d] / l_j ; emit TT = bf16(T)^T  [d][j]
// ---------------------------------------------------------------------------
__global__ __launch_bounds__(256) void k1(const float* __restrict__ cw1, const float* __restrict__ qw2,
                                          const int* __restrict__ cmask,
                                          const bf16* __restrict__ cw3, const bf16* __restrict__ cT,
                                          const bf16* __restrict__ qb, bf16* __restrict__ TT) {
  __shared__ bf16  qs[32 * 136];     // [j][d]
  __shared__ bf16  cw3t[64 * 136];   // [k][d]   (also reused as TT staging at end)
  __shared__ bf16  cTt[128 * 72];    // [d][k]
  __shared__ bf16  PT[32 * 72];      // [j][k]
  __shared__ float lred[4][32];
  __shared__ float lfin[32];
  const int js = blockIdx.x, b = blockIdx.y;
  const int j0 = js * 32;
  const int t = threadIdx.x;
  const int w = t >> 6, lane = t & 63, quad = lane >> 4, l15 = lane & 15;

#pragma unroll
  for (int idx = t; idx < 512; idx += 256) {
    const int row = idx >> 4, ch = idx & 15;
    *(bf16x8*)&qs[row * 136 + ch * 8] =
        *(const bf16x8*)(qb + ((size_t)(b * LQ_ + j0 + row) * D_ + ch * 8));
  }
  const f32x4 z = {0.f, 0.f, 0.f, 0.f};
  f32x4 Tacc[2][2] = {{z, z}, {z, z}};
  float lacc0 = 0.f, lacc1 = 0.f;
  __syncthreads();

  for (int kt = 0; kt < 16; ++kt) {
    const int k0g = kt * 64;
#pragma unroll
    for (int idx = t; idx < 1024; idx += 256) {
      const int row = idx >> 4, ch = idx & 15;
      *(bf16x8*)&cw3t[row * 136 + ch * 8] =
          *(const bf16x8*)(cw3 + ((size_t)(b * LC_ + k0g + row) * D_ + ch * 8));
    }
#pragma unroll
    for (int idx = t; idx < 1024; idx += 256) {
      const int row = idx >> 3, ch = idx & 7;
      *(bf16x8*)&cTt[row * 72 + ch * 8] =
          *(const bf16x8*)(cT + ((size_t)(b * D_ + row) * LC_ + k0g + ch * 8));
    }
    __syncthreads();

    // GEMM1: S tile, wave handles k-rows [w*16, w*16+16) x 32 j
    f32x4 S0 = z, S1 = z;
#pragma unroll
    for (int ks = 0; ks < 4; ++ks) {
      bf16x8 a  = *(bf16x8*)&cw3t[(w * 16 + l15) * 136 + ks * 32 + quad * 8];
      bf16x8 b0 = *(bf16x8*)&qs[l15 * 136 + ks * 32 + quad * 8];
      bf16x8 b1 = *(bf16x8*)&qs[(16 + l15) * 136 + ks * 32 + quad * 8];
      S0 = mfma16(a, b0, S0);
      S1 = mfma16(a, b1, S1);
    }
    const float qv0 = qw2[b * LQ_ + j0 + l15];
    const float qv1 = qw2[b * LQ_ + j0 + 16 + l15];
    bf16x4 pk0, pk1;
#pragma unroll
    for (int rr = 0; rr < 4; ++rr) {
      const int krow = k0g + w * 16 + quad * 4 + rr;
      const float c1 = cw1[b * LC_ + krow];
      const int   cm = cmask[b * LC_ + krow];
      const float p0 = cm ? 0.f : __expf(S0[rr] + c1 + qv0);
      const float p1 = cm ? 0.f : __expf(S1[rr] + c1 + qv1);
      lacc0 += p0; lacc1 += p1;
      pk0[rr] = (bf16)p0; pk1[rr] = (bf16)p1;
    }
    *(bf16x4*)&PT[l15 * 72 + w * 16 + quad * 4] = pk0;
    *(bf16x4*)&PT[(16 + l15) * 72 + w * 16 + quad * 4] = pk1;
    __syncthreads();

    // GEMM2: T_unnorm[j, d-slice] += P^T @ c ; wave owns d in [w*32, w*32+32)
#pragma unroll
    for (int ks = 0; ks < 2; ++ks) {
      bf16x8 a0 = *(bf16x8*)&PT[l15 * 72 + ks * 32 + quad * 8];
      bf16x8 a1 = *(bf16x8*)&PT[(16 + l15) * 72 + ks * 32 + quad * 8];
      bf16x8 b0 = *(bf16x8*)&cTt[(w * 32 + l15) * 72 + ks * 32 + quad * 8];
      bf16x8 b1 = *(bf16x8*)&cTt[(w * 32 + 16 + l15) * 72 + ks * 32 + quad * 8];
      Tacc[0][0] = mfma16(a0, b0, Tacc[0][0]);
      Tacc[0][1] = mfma16(a0, b1, Tacc[0][1]);
      Tacc[1][0] = mfma16(a1, b0, Tacc[1][0]);
      Tacc[1][1] = mfma16(a1, b1, Tacc[1][1]);
    }
    __syncthreads();
  }

  // l_j: quad-reduce in-wave, then cross-wave via LDS
  lacc0 += __shfl_xor(lacc0, 16); lacc0 += __shfl_xor(lacc0, 32);
  lacc1 += __shfl_xor(lacc1, 16); lacc1 += __shfl_xor(lacc1, 32);
  if (lane < 16) { lred[w][l15] = lacc0; lred[w][16 + l15] = lacc1; }
  __syncthreads();
  if (t < 32) lfin[t] = lred[0][t] + lred[1][t] + lred[2][t] + lred[3][t];
  __syncthreads();

  bf16* TTa = cw3t;  // reuse as [128 d][40] staging
#pragma unroll
  for (int mt = 0; mt < 2; ++mt) {
#pragma unroll
    for (int nt = 0; nt < 2; ++nt) {
      const int d = w * 32 + nt * 16 + l15;
      bf16x4 pk;
#pragma unroll
      for (int rr = 0; rr < 4; ++rr) {
        const int j = mt * 16 + quad * 4 + rr;
        pk[rr] = (bf16)(Tacc[mt][nt][rr] / lfin[j]);
      }
      *(bf16x4*)&TTa[d * 40 + mt * 16 + quad * 4] = pk;
    }
  }
  __syncthreads();
  if (t < 128) {
    bf16* dst = TT + ((size_t)(b * D_ + t) * LQ_ + j0);
#pragma unroll
    for (int v = 0; v < 4; ++v)
      *(bf16x8*)(dst + v * 8) = *(bf16x8*)&TTa[t * 40 + v * 8];
  }
}

// ---------------------------------------------------------------------------
// K2: per (b, 64-row i-tile): row softmax (mask=q_mask on j), A = S1@q,
//     Batt = S1@T ; write [c | A | c*A | c*Batt]
// ---------------------------------------------------------------------------
__global__ __launch_bounds__(256) void k2(const float* __restrict__ c, const float* __restrict__ cw1,
                                          const float* __restrict__ qw2, const int* __restrict__ qmask,
                                          const bf16* __restrict__ cw3, const bf16* __restrict__ qb,
                                          const bf16* __restrict__ qT, const bf16* __restrict__ TT,
                                          float* __restrict__ out) {
  __shared__ bf16 cw3i[64 * 136];   // [i][d]
  __shared__ bf16 qsl[32 * 136];    // [j][d]
  __shared__ bf16 qTsl[128 * 40];   // [d][j]
  __shared__ bf16 TTsl[128 * 40];   // [d][j]
  __shared__ bf16 P1[64 * 40];      // [i][j]
  const int it = blockIdx.x, b = blockIdx.y;
  const int i0 = it * 64;
  const int t = threadIdx.x;
  const int w = t >> 6, lane = t & 63, quad = lane >> 4, l15 = lane & 15;

#pragma unroll
  for (int idx = t; idx < 1024; idx += 256) {
    const int row = idx >> 4, ch = idx & 15;
    *(bf16x8*)&cw3i[row * 136 + ch * 8] =
        *(const bf16x8*)(cw3 + ((size_t)(b * LC_ + i0 + row) * D_ + ch * 8));
  }
  const f32x4 z = {0.f, 0.f, 0.f, 0.f};
  f32x4 Aacc[8], Bacc[8];
#pragma unroll
  for (int n = 0; n < 8; ++n) { Aacc[n] = z; Bacc[n] = z; }
  float lacc[4] = {0.f, 0.f, 0.f, 0.f};
  __syncthreads();

  for (int jt = 0; jt < 4; ++jt) {
    const int j0 = jt * 32;
#pragma unroll
    for (int idx = t; idx < 512; idx += 256) {
      const int row = idx >> 4, ch = idx & 15;
      *(bf16x8*)&qsl[row * 136 + ch * 8] =
          *(const bf16x8*)(qb + ((size_t)(b * LQ_ + j0 + row) * D_ + ch * 8));
    }
#pragma unroll
    for (int idx = t; idx < 512; idx += 256) {
      const int row = idx >> 2, ch = idx & 3;
      *(bf16x8*)&qTsl[row * 40 + ch * 8] =
          *(const bf16x8*)(qT + ((size_t)(b * D_ + row) * LQ_ + j0 + ch * 8));
    }
#pragma unroll
    for (int idx = t; idx < 512; idx += 256) {
      const int row = idx >> 2, ch = idx & 3;
      *(bf16x8*)&TTsl[row * 40 + ch * 8] =
          *(const bf16x8*)(TT + ((size_t)(b * D_ + row) * LQ_ + j0 + ch * 8));
    }
    __syncthreads();

    // GEMM1: S tile; wave owns i-rows [w*16, w*16+16)
    f32x4 S0 = z, S1 = z;
#pragma unroll
    for (int ks = 0; ks < 4; ++ks) {
      bf16x8 a  = *(bf16x8*)&cw3i[(w * 16 + l15) * 136 + ks * 32 + quad * 8];
      bf16x8 b0 = *(bf16x8*)&qsl[l15 * 136 + ks * 32 + quad * 8];
      bf16x8 b1 = *(bf16x8*)&qsl[(16 + l15) * 136 + ks * 32 + quad * 8];
      S0 = mfma16(a, b0, S0);
      S1 = mfma16(a, b1, S1);
    }
    const float qv0 = qw2[b * LQ_ + j0 + l15];
    const float qv1 = qw2[b * LQ_ + j0 + 16 + l15];
    const int   qm0 = qmask[b * LQ_ + j0 + l15];
    const int   qm1 = qmask[b * LQ_ + j0 + 16 + l15];
#pragma unroll
    for (int rr = 0; rr < 4; ++rr) {
      const int irow = i0 + w * 16 + quad * 4 + rr;
      const float c1 = cw1[b * LC_ + irow];
      const float p0 = qm0 ? 0.f : __expf(S0[rr] + c1 + qv0);
      const float p1 = qm1 ? 0.f : __expf(S1[rr] + c1 + qv1);
      lacc[rr] += p0 + p1;
      P1[(w * 16 + quad * 4 + rr) * 40 + l15] = (bf16)p0;
      P1[(w * 16 + quad * 4 + rr) * 40 + 16 + l15] = (bf16)p1;
    }
    __syncthreads();

    // GEMM2/3: one A-frag reused for 16 MFMAs
    bf16x8 aP = *(bf16x8*)&P1[(w * 16 + l15) * 40 + quad * 8];
#pragma unroll
    for (int nt = 0; nt < 8; ++nt) {
      bf16x8 bq = *(bf16x8*)&qTsl[(nt * 16 + l15) * 40 + quad * 8];
      bf16x8 bt = *(bf16x8*)&TTsl[(nt * 16 + l15) * 40 + quad * 8];
      Aacc[nt] = mfma16(aP, bq, Aacc[nt]);
      Bacc[nt] = mfma16(aP, bt, Bacc[nt]);
    }
    __syncthreads();
  }

  // l_i: butterfly over the 16 j-lanes
#pragma unroll
  for (int rr = 0; rr < 4; ++rr) {
    float v = lacc[rr];
    v += __shfl_xor(v, 1); v += __shfl_xor(v, 2);
    v += __shfl_xor(v, 4); v += __shfl_xor(v, 8);
    lacc[rr] = 1.f / v;
  }

#pragma unroll
  for (int nt = 0; nt < 8; ++nt) {
    const int d = nt * 16 + l15;
#pragma unroll
    for (int rr = 0; rr < 4; ++rr) {
      const int irow = i0 + w * 16 + quad * 4 + rr;
      const float Av = Aacc[nt][rr] * lacc[rr];
      const float Bv = Bacc[nt][rr] * lacc[rr];
      const float cv = c[(size_t)(b * LC_ + irow) * D_ + d];
      float* ob = out + (size_t)(b * LC_ + irow) * 512;
      ob[128 + d] = Av;
      ob[256 + d] = cv * Av;
      ob[384 + d] = cv * Bv;
    }
  }
  // exact fp32 copy of c_rep into out[..., 0:128]
#pragma unroll
  for (int idx = t; idx < 2048; idx += 256) {
    const int row = idx >> 5, seg = idx & 31;
    const float4 v = ((const float4*)(c + (size_t)(b * LC_ + i0 + row) * D_))[seg];
    ((float4*)(out + (size_t)(b * LC_ + i0 + row) * 512))[seg] = v;
  }
}

// ---------------------------------------------------------------------------
extern "C" void kernel_launch(void* const* d_in, const int* in_sizes, int n_in,
                              void* d_out, int out_size, void* d_ws, size_t ws_size,
                              hipStream_t stream) {
  (void)in_sizes; (void)n_in; (void)out_size; (void)ws_size;
  const float* c     = (const float*)d_in[0];
  const float* q     = (const float*)d_in[1];
  const int*   cmask = (const int*)d_in[2];
  const int*   qmask = (const int*)d_in[3];
  const float* w     = (const float*)d_in[4];
  float* out = (float*)d_out;

  // workspace layout (40.1 MB total)
  char* ws = (char*)d_ws;
  float* cw1 = (float*)(ws + 0);          //  64*1024 f32
  float* qw2 = (float*)(ws + 262144);     //  64*128  f32
  bf16*  cw3 = (bf16*)(ws + 294912);      //  64*1024*128 bf16  (c*w3)
  bf16*  cT  = (bf16*)(ws + 17072128);    //  64*128*1024 bf16  (c transposed)
  bf16*  qb  = (bf16*)(ws + 33849344);    //  64*128*128 bf16
  bf16*  qT  = (bf16*)(ws + 35946496);    //  64*128*128 bf16  (q transposed)
  bf16*  TT  = (bf16*)(ws + 38043648);    //  64*128*128 bf16  (T transposed)

  k0c<<<dim3(8, 64), 256, 0, stream>>>(c, w, cw1, cw3, cT);
  k0q<<<dim3(64), 256, 0, stream>>>(q, w, qw2, qb, qT);
  k1<<<dim3(4, 64), 256, 0, stream>>>(cw1, qw2, cmask, cw3, cT, qb, TT);
  k2<<<dim3(16, 64), 256, 0, stream>>>(c, cw1, qw2, qmask, cw3, qb, qT, TT, out);
}

// Round 2
// 246.783 us; speedup vs baseline: 1.0777x; 1.0777x over previous
//
#include <hip/hip_runtime.h>
#include <hip/hip_bf16.h>
#include <cstdint>
#include <cstddef>

// Problem constants
#define B_   64
#define LC_  1024
#define LQ_  128
#define D_   128

typedef __bf16 bf16;
typedef bf16  bf16x8 __attribute__((ext_vector_type(8)));
typedef bf16  bf16x4 __attribute__((ext_vector_type(4)));
typedef float f32x4  __attribute__((ext_vector_type(4)));

__device__ __forceinline__ f32x4 mfma16(bf16x8 a, bf16x8 b, f32x4 c) {
  return __builtin_amdgcn_mfma_f32_16x16x32_bf16(a, b, c, 0, 0, 0);
}

// ---------------------------------------------------------------------------
// K0c: per (b, 128-row k-slice): cw1[b,k] = c.w1 ; cw3 = bf16(c*w3) ; cT = bf16(c)^T
// ---------------------------------------------------------------------------
__global__ __launch_bounds__(256) void k0c(const float* __restrict__ c, const float* __restrict__ w,
                                           float* __restrict__ cw1, bf16* __restrict__ cw3,
                                           bf16* __restrict__ cT) {
  __shared__ float w1s[128];
  __shared__ float w3s[128];
  __shared__ bf16  ctile[128 * 132];
  const int b = blockIdx.y, ks = blockIdx.x;
  const int k0 = ks * 128;
  const int t = threadIdx.x;
  if (t < 128) { w1s[t] = w[t]; w3s[t] = w[256 + t]; }
  __syncthreads();
  {
    const int r = t >> 1, d0 = (t & 1) * 64;
    const float* crow = c + ((size_t)(b * LC_ + k0 + r) * D_ + d0);
    bf16* orow = cw3 + ((size_t)(b * LC_ + k0 + r) * D_ + d0);
    float dot = 0.f;
#pragma unroll
    for (int v = 0; v < 8; ++v) {
      const float4 f0 = ((const float4*)crow)[v * 2 + 0];
      const float4 f1 = ((const float4*)crow)[v * 2 + 1];
      const int dd = d0 + v * 8;
      dot += f0.x * w1s[dd + 0] + f0.y * w1s[dd + 1] + f0.z * w1s[dd + 2] + f0.w * w1s[dd + 3]
           + f1.x * w1s[dd + 4] + f1.y * w1s[dd + 5] + f1.z * w1s[dd + 6] + f1.w * w1s[dd + 7];
      bf16* cr = &ctile[r * 132 + dd];
      cr[0] = (bf16)f0.x; cr[1] = (bf16)f0.y; cr[2] = (bf16)f0.z; cr[3] = (bf16)f0.w;
      cr[4] = (bf16)f1.x; cr[5] = (bf16)f1.y; cr[6] = (bf16)f1.z; cr[7] = (bf16)f1.w;
      bf16x8 o;
      o[0] = (bf16)(f0.x * w3s[dd + 0]); o[1] = (bf16)(f0.y * w3s[dd + 1]);
      o[2] = (bf16)(f0.z * w3s[dd + 2]); o[3] = (bf16)(f0.w * w3s[dd + 3]);
      o[4] = (bf16)(f1.x * w3s[dd + 4]); o[5] = (bf16)(f1.y * w3s[dd + 5]);
      o[6] = (bf16)(f1.z * w3s[dd + 6]); o[7] = (bf16)(f1.w * w3s[dd + 7]);
      *(bf16x8*)(orow + v * 8) = o;
    }
    dot += __shfl_xor(dot, 1);
    if ((t & 1) == 0) cw1[b * LC_ + k0 + r] = dot;
  }
  __syncthreads();
  {
    const int d = t >> 1, kh = (t & 1) * 64;
    bf16* trow = cT + ((size_t)(b * D_ + d) * LC_ + k0 + kh);
#pragma unroll
    for (int v = 0; v < 8; ++v) {
      bf16x8 o;
#pragma unroll
      for (int e = 0; e < 8; ++e) o[e] = ctile[(kh + v * 8 + e) * 132 + d];
      *(bf16x8*)(trow + v * 8) = o;
    }
  }
}

// ---------------------------------------------------------------------------
// K0q: per batch: qw2[b,j] = q.w2 ; qb = bf16(q) ; qT = bf16(q)^T
// ---------------------------------------------------------------------------
__global__ __launch_bounds__(256) void k0q(const float* __restrict__ q, const float* __restrict__ w,
                                           float* __restrict__ qw2, bf16* __restrict__ qb,
                                           bf16* __restrict__ qT) {
  __shared__ float w2s[128];
  __shared__ bf16  qtile[128 * 132];
  const int b = blockIdx.x;
  const int t = threadIdx.x;
  if (t < 128) w2s[t] = w[128 + t];
  __syncthreads();
  {
    const int r = t >> 1, d0 = (t & 1) * 64;
    const float* qrow = q + ((size_t)(b * LQ_ + r) * D_ + d0);
    bf16* orow = qb + ((size_t)(b * LQ_ + r) * D_ + d0);
    float dot = 0.f;
#pragma unroll
    for (int v = 0; v < 8; ++v) {
      const float4 f0 = ((const float4*)qrow)[v * 2 + 0];
      const float4 f1 = ((const float4*)qrow)[v * 2 + 1];
      const int dd = d0 + v * 8;
      dot += f0.x * w2s[dd + 0] + f0.y * w2s[dd + 1] + f0.z * w2s[dd + 2] + f0.w * w2s[dd + 3]
           + f1.x * w2s[dd + 4] + f1.y * w2s[dd + 5] + f1.z * w2s[dd + 6] + f1.w * w2s[dd + 7];
      bf16x8 o;
      o[0] = (bf16)f0.x; o[1] = (bf16)f0.y; o[2] = (bf16)f0.z; o[3] = (bf16)f0.w;
      o[4] = (bf16)f1.x; o[5] = (bf16)f1.y; o[6] = (bf16)f1.z; o[7] = (bf16)f1.w;
      bf16* qr = &qtile[r * 132 + dd];
#pragma unroll
      for (int e = 0; e < 8; ++e) qr[e] = o[e];
      *(bf16x8*)(orow + v * 8) = o;
    }
    dot += __shfl_xor(dot, 1);
    if ((t & 1) == 0) qw2[b * LQ_ + r] = dot;
  }
  __syncthreads();
  {
    const int d = t >> 1, jh = (t & 1) * 64;
    bf16* trow = qT + ((size_t)(b * D_ + d) * LQ_ + jh);
#pragma unroll
    for (int v = 0; v < 8; ++v) {
      bf16x8 o;
#pragma unroll
      for (int e = 0; e < 8; ++e) o[e] = qtile[(jh + v * 8 + e) * 132 + d];
      *(bf16x8*)(trow + v * 8) = o;
    }
  }
}

// ---------------------------------------------------------------------------
// K1p: per (b, k-half ks, 32-wide j-slice): partial column-softmax sums.
//   Tpart[(b,ks,js)][j][d] = sum_{k in half} P[k,j] c[k,d]   (fp32, unnormalized)
//   lpart[(b,ks)][j]       = sum_{k in half} P[k,j]
// ---------------------------------------------------------------------------
__global__ __launch_bounds__(256) void k1p(const float* __restrict__ cw1, const float* __restrict__ qw2,
                                           const int* __restrict__ cmask,
                                           const bf16* __restrict__ cw3, const bf16* __restrict__ cT,
                                           const bf16* __restrict__ qb,
                                           float* __restrict__ Tpart, float* __restrict__ lpart) {
  __shared__ bf16  qs[32 * 136];     // [j][d]
  __shared__ bf16  cw3t[64 * 136];   // [k][d]
  __shared__ bf16  cTt[128 * 72];    // [d][k]
  __shared__ bf16  PT[32 * 72];      // [j][k]
  __shared__ float lred[4][32];
  const int bx = blockIdx.x;
  const int ks = bx >> 2, js = bx & 3;
  const int b = blockIdx.y;
  const int j0 = js * 32;
  const int t = threadIdx.x;
  const int w = t >> 6, lane = t & 63, quad = lane >> 4, l15 = lane & 15;

#pragma unroll
  for (int idx = t; idx < 512; idx += 256) {
    const int row = idx >> 4, ch = idx & 15;
    *(bf16x8*)&qs[row * 136 + ch * 8] =
        *(const bf16x8*)(qb + ((size_t)(b * LQ_ + j0 + row) * D_ + ch * 8));
  }
  const f32x4 z = {0.f, 0.f, 0.f, 0.f};
  f32x4 Tacc[2][2] = {{z, z}, {z, z}};
  float lacc0 = 0.f, lacc1 = 0.f;
  __syncthreads();

  for (int kt = 0; kt < 8; ++kt) {
    const int k0g = ks * 512 + kt * 64;
#pragma unroll
    for (int idx = t; idx < 1024; idx += 256) {
      const int row = idx >> 4, ch = idx & 15;
      *(bf16x8*)&cw3t[row * 136 + ch * 8] =
          *(const bf16x8*)(cw3 + ((size_t)(b * LC_ + k0g + row) * D_ + ch * 8));
    }
#pragma unroll
    for (int idx = t; idx < 1024; idx += 256) {
      const int row = idx >> 3, ch = idx & 7;
      *(bf16x8*)&cTt[row * 72 + ch * 8] =
          *(const bf16x8*)(cT + ((size_t)(b * D_ + row) * LC_ + k0g + ch * 8));
    }
    __syncthreads();

    // GEMM1: S tile, wave handles k-rows [w*16, w*16+16) x 32 j
    f32x4 S0 = z, S1 = z;
#pragma unroll
    for (int kk = 0; kk < 4; ++kk) {
      bf16x8 a  = *(bf16x8*)&cw3t[(w * 16 + l15) * 136 + kk * 32 + quad * 8];
      bf16x8 b0 = *(bf16x8*)&qs[l15 * 136 + kk * 32 + quad * 8];
      bf16x8 b1 = *(bf16x8*)&qs[(16 + l15) * 136 + kk * 32 + quad * 8];
      S0 = mfma16(a, b0, S0);
      S1 = mfma16(a, b1, S1);
    }
    const float qv0 = qw2[b * LQ_ + j0 + l15];
    const float qv1 = qw2[b * LQ_ + j0 + 16 + l15];
    bf16x4 pk0, pk1;
#pragma unroll
    for (int rr = 0; rr < 4; ++rr) {
      const int krow = k0g + w * 16 + quad * 4 + rr;
      const float c1 = cw1[b * LC_ + krow];
      const int   cm = cmask[b * LC_ + krow];
      const float p0 = cm ? 0.f : __expf(S0[rr] + c1 + qv0);
      const float p1 = cm ? 0.f : __expf(S1[rr] + c1 + qv1);
      lacc0 += p0; lacc1 += p1;
      pk0[rr] = (bf16)p0; pk1[rr] = (bf16)p1;
    }
    *(bf16x4*)&PT[l15 * 72 + w * 16 + quad * 4] = pk0;
    *(bf16x4*)&PT[(16 + l15) * 72 + w * 16 + quad * 4] = pk1;
    __syncthreads();

    // GEMM2: T_part[j, d-slice] += P^T @ c ; wave owns d in [w*32, w*32+32)
#pragma unroll
    for (int kk = 0; kk < 2; ++kk) {
      bf16x8 a0 = *(bf16x8*)&PT[l15 * 72 + kk * 32 + quad * 8];
      bf16x8 a1 = *(bf16x8*)&PT[(16 + l15) * 72 + kk * 32 + quad * 8];
      bf16x8 b0 = *(bf16x8*)&cTt[(w * 32 + l15) * 72 + kk * 32 + quad * 8];
      bf16x8 b1 = *(bf16x8*)&cTt[(w * 32 + 16 + l15) * 72 + kk * 32 + quad * 8];
      Tacc[0][0] = mfma16(a0, b0, Tacc[0][0]);
      Tacc[0][1] = mfma16(a0, b1, Tacc[0][1]);
      Tacc[1][0] = mfma16(a1, b0, Tacc[1][0]);
      Tacc[1][1] = mfma16(a1, b1, Tacc[1][1]);
    }
    __syncthreads();
  }

  // partial l_j: quad-reduce in-wave, then cross-wave via LDS
  lacc0 += __shfl_xor(lacc0, 16); lacc0 += __shfl_xor(lacc0, 32);
  lacc1 += __shfl_xor(lacc1, 16); lacc1 += __shfl_xor(lacc1, 32);
  if (lane < 16) { lred[w][l15] = lacc0; lred[w][16 + l15] = lacc1; }
  __syncthreads();
  if (t < 32)
    lpart[(size_t)(b * 2 + ks) * 128 + j0 + t] = lred[0][t] + lred[1][t] + lred[2][t] + lred[3][t];

  // write fp32 partial T tile [32 j][128 d]
  float* tp = Tpart + ((size_t)((b * 2 + ks) * 4 + js)) * (32 * 128);
#pragma unroll
  for (int mt = 0; mt < 2; ++mt)
#pragma unroll
    for (int nt = 0; nt < 2; ++nt)
#pragma unroll
      for (int rr = 0; rr < 4; ++rr)
        tp[(mt * 16 + quad * 4 + rr) * 128 + w * 32 + nt * 16 + l15] = Tacc[mt][nt][rr];
}

// ---------------------------------------------------------------------------
// K1r: reduce the two k-halves, normalize by l_j, emit TT = bf16(T)^T [d][j]
// ---------------------------------------------------------------------------
__global__ __launch_bounds__(256) void k1r(const float* __restrict__ Tpart,
                                           const float* __restrict__ lpart,
                                           bf16* __restrict__ TT) {
  __shared__ float Tsum[32 * 132];
  __shared__ float linv[32];
  const int js = blockIdx.x, b = blockIdx.y;
  const int j0 = js * 32;
  const int t = threadIdx.x;
  const float4* p0 = (const float4*)(Tpart + ((size_t)((b * 2 + 0) * 4 + js)) * (32 * 128));
  const float4* p1 = (const float4*)(Tpart + ((size_t)((b * 2 + 1) * 4 + js)) * (32 * 128));
#pragma unroll
  for (int idx = t; idx < 1024; idx += 256) {
    const int row = idx >> 5, seg = idx & 31;
    const float4 v0 = p0[idx];
    const float4 v1 = p1[idx];
    float4 s;
    s.x = v0.x + v1.x; s.y = v0.y + v1.y; s.z = v0.z + v1.z; s.w = v0.w + v1.w;
    *(float4*)&Tsum[row * 132 + seg * 4] = s;
  }
  if (t < 32)
    linv[t] = 1.f / (lpart[(size_t)(b * 2 + 0) * 128 + j0 + t] +
                     lpart[(size_t)(b * 2 + 1) * 128 + j0 + t]);
  __syncthreads();
  const int d = t >> 1, jh = (t & 1) * 16;
  bf16x8 o0, o1;
#pragma unroll
  for (int e = 0; e < 8; ++e) {
    o0[e] = (bf16)(Tsum[(jh + e) * 132 + d] * linv[jh + e]);
    o1[e] = (bf16)(Tsum[(jh + 8 + e) * 132 + d] * linv[jh + 8 + e]);
  }
  bf16* dst = TT + ((size_t)(b * D_ + d) * LQ_ + j0 + jh);
  *(bf16x8*)dst = o0;
  *(bf16x8*)(dst + 8) = o1;
}

// ---------------------------------------------------------------------------
// K2: per (b, 64-row i-tile): row softmax (mask=q_mask on j), A = S1@q,
//     Batt = S1@T ; write [c | A | c*A | c*Batt] with float4 stores via LDS.
// ---------------------------------------------------------------------------
__global__ __launch_bounds__(256) void k2(const float* __restrict__ c, const float* __restrict__ cw1,
                                          const float* __restrict__ qw2, const int* __restrict__ qmask,
                                          const bf16* __restrict__ cw3, const bf16* __restrict__ qb,
                                          const bf16* __restrict__ qT, const bf16* __restrict__ TT,
                                          float* __restrict__ out) {
  // union LDS: loop phase 51712 B / epilogue phase 33792 B
  __shared__ __align__(16) char smem[51712];
  bf16* cw3i = (bf16*)(smem);            // [64][136]
  bf16* qsl  = (bf16*)(smem + 17408);    // [32][136]
  bf16* qTsl = (bf16*)(smem + 26112);    // [128][40]
  bf16* TTsl = (bf16*)(smem + 36352);    // [128][40]
  bf16* P1   = (bf16*)(smem + 46592);    // [64][40]
  float* A32 = (float*)(smem);           // [32][132] epilogue
  float* B32 = (float*)(smem + 16896);   // [32][132] epilogue
  const int it = blockIdx.x, b = blockIdx.y;
  const int i0 = it * 64;
  const int t = threadIdx.x;
  const int w = t >> 6, lane = t & 63, quad = lane >> 4, l15 = lane & 15;

#pragma unroll
  for (int idx = t; idx < 1024; idx += 256) {
    const int row = idx >> 4, ch = idx & 15;
    *(bf16x8*)&cw3i[row * 136 + ch * 8] =
        *(const bf16x8*)(cw3 + ((size_t)(b * LC_ + i0 + row) * D_ + ch * 8));
  }
  const f32x4 z = {0.f, 0.f, 0.f, 0.f};
  f32x4 Aacc[8], Bacc[8];
#pragma unroll
  for (int n = 0; n < 8; ++n) { Aacc[n] = z; Bacc[n] = z; }
  float lacc[4] = {0.f, 0.f, 0.f, 0.f};
  __syncthreads();

  for (int jt = 0; jt < 4; ++jt) {
    const int j0 = jt * 32;
#pragma unroll
    for (int idx = t; idx < 512; idx += 256) {
      const int row = idx >> 4, ch = idx & 15;
      *(bf16x8*)&qsl[row * 136 + ch * 8] =
          *(const bf16x8*)(qb + ((size_t)(b * LQ_ + j0 + row) * D_ + ch * 8));
    }
#pragma unroll
    for (int idx = t; idx < 512; idx += 256) {
      const int row = idx >> 2, ch = idx & 3;
      *(bf16x8*)&qTsl[row * 40 + ch * 8] =
          *(const bf16x8*)(qT + ((size_t)(b * D_ + row) * LQ_ + j0 + ch * 8));
    }
#pragma unroll
    for (int idx = t; idx < 512; idx += 256) {
      const int row = idx >> 2, ch = idx & 3;
      *(bf16x8*)&TTsl[row * 40 + ch * 8] =
          *(const bf16x8*)(TT + ((size_t)(b * D_ + row) * LQ_ + j0 + ch * 8));
    }
    __syncthreads();

    // GEMM1: S tile; wave owns i-rows [w*16, w*16+16)
    f32x4 S0 = z, S1 = z;
#pragma unroll
    for (int kk = 0; kk < 4; ++kk) {
      bf16x8 a  = *(bf16x8*)&cw3i[(w * 16 + l15) * 136 + kk * 32 + quad * 8];
      bf16x8 b0 = *(bf16x8*)&qsl[l15 * 136 + kk * 32 + quad * 8];
      bf16x8 b1 = *(bf16x8*)&qsl[(16 + l15) * 136 + kk * 32 + quad * 8];
      S0 = mfma16(a, b0, S0);
      S1 = mfma16(a, b1, S1);
    }
    const float qv0 = qw2[b * LQ_ + j0 + l15];
    const float qv1 = qw2[b * LQ_ + j0 + 16 + l15];
    const int   qm0 = qmask[b * LQ_ + j0 + l15];
    const int   qm1 = qmask[b * LQ_ + j0 + 16 + l15];
#pragma unroll
    for (int rr = 0; rr < 4; ++rr) {
      const int irow = i0 + w * 16 + quad * 4 + rr;
      const float c1 = cw1[b * LC_ + irow];
      const float p0 = qm0 ? 0.f : __expf(S0[rr] + c1 + qv0);
      const float p1 = qm1 ? 0.f : __expf(S1[rr] + c1 + qv1);
      lacc[rr] += p0 + p1;
      P1[(w * 16 + quad * 4 + rr) * 40 + l15] = (bf16)p0;
      P1[(w * 16 + quad * 4 + rr) * 40 + 16 + l15] = (bf16)p1;
    }
    __syncthreads();

    // GEMM2/3: one A-frag reused for 16 MFMAs
    bf16x8 aP = *(bf16x8*)&P1[(w * 16 + l15) * 40 + quad * 8];
#pragma unroll
    for (int nt = 0; nt < 8; ++nt) {
      bf16x8 bq = *(bf16x8*)&qTsl[(nt * 16 + l15) * 40 + quad * 8];
      bf16x8 bt = *(bf16x8*)&TTsl[(nt * 16 + l15) * 40 + quad * 8];
      Aacc[nt] = mfma16(aP, bq, Aacc[nt]);
      Bacc[nt] = mfma16(aP, bt, Bacc[nt]);
    }
    __syncthreads();
  }

  // l_i inverse: butterfly over the 16 j-lanes (stays within quad)
#pragma unroll
  for (int rr = 0; rr < 4; ++rr) {
    float v = lacc[rr];
    v += __shfl_xor(v, 1); v += __shfl_xor(v, 2);
    v += __shfl_xor(v, 4); v += __shfl_xor(v, 8);
    lacc[rr] = 1.f / v;
  }

  // epilogue: two 32-row passes; stage A,B fp32 in LDS, fused float4 writes
#pragma unroll
  for (int h = 0; h < 2; ++h) {
    if ((w >> 1) == h) {
      const int lrow0 = (w & 1) * 16 + quad * 4;
#pragma unroll
      for (int nt = 0; nt < 8; ++nt)
#pragma unroll
        for (int rr = 0; rr < 4; ++rr) {
          A32[(lrow0 + rr) * 132 + nt * 16 + l15] = Aacc[nt][rr] * lacc[rr];
          B32[(lrow0 + rr) * 132 + nt * 16 + l15] = Bacc[nt][rr] * lacc[rr];
        }
    }
    __syncthreads();
#pragma unroll
    for (int idx = t; idx < 1024; idx += 256) {
      const int lrow = idx >> 5, seg = idx & 31;
      const size_t grow = (size_t)(b * LC_ + i0 + h * 32 + lrow);
      const float4 c4 = ((const float4*)(c + grow * D_))[seg];
      const float4 a4 = *(float4*)&A32[lrow * 132 + seg * 4];
      const float4 b4 = *(float4*)&B32[lrow * 132 + seg * 4];
      float4* ob = (float4*)(out + grow * 512);
      ob[seg] = c4;
      ob[32 + seg] = a4;
      float4 ca; ca.x = c4.x * a4.x; ca.y = c4.y * a4.y; ca.z = c4.z * a4.z; ca.w = c4.w * a4.w;
      ob[64 + seg] = ca;
      float4 cb; cb.x = c4.x * b4.x; cb.y = c4.y * b4.y; cb.z = c4.z * b4.z; cb.w = c4.w * b4.w;
      ob[96 + seg] = cb;
    }
    __syncthreads();
  }
}

// ---------------------------------------------------------------------------
extern "C" void kernel_launch(void* const* d_in, const int* in_sizes, int n_in,
                              void* d_out, int out_size, void* d_ws, size_t ws_size,
                              hipStream_t stream) {
  (void)in_sizes; (void)n_in; (void)out_size; (void)ws_size;
  const float* c     = (const float*)d_in[0];
  const float* q     = (const float*)d_in[1];
  const int*   cmask = (const int*)d_in[2];
  const int*   qmask = (const int*)d_in[3];
  const float* w     = (const float*)d_in[4];
  float* out = (float*)d_out;

  // workspace layout (40.1 MB)
  char* ws = (char*)d_ws;
  float* cw1 = (float*)(ws + 0);          //  64*1024 f32
  float* qw2 = (float*)(ws + 262144);     //  64*128  f32
  bf16*  cw3 = (bf16*)(ws + 294912);      //  64*1024*128 bf16  (c*w3)
  bf16*  cT  = (bf16*)(ws + 17072128);    //  64*128*1024 bf16  (c transposed)
  bf16*  qb  = (bf16*)(ws + 33849344);    //  64*128*128 bf16
  bf16*  qT  = (bf16*)(ws + 35946496);    //  64*128*128 bf16  (q transposed)
  bf16*  TT  = (bf16*)(ws + 38043648);    //  64*128*128 bf16  (T transposed)

  // k-split partials live in d_out scratch (fully overwritten by k2 afterwards)
  float* Tpart = out;                     //  64*2*4*32*128 f32 = 8.39 MB
  float* lpart = out + 2097152;           //  64*2*128 f32

  k0c<<<dim3(8, 64), 256, 0, stream>>>(c, w, cw1, cw3, cT);
  k0q<<<dim3(64), 256, 0, stream>>>(q, w, qw2, qb, qT);
  k1p<<<dim3(8, 64), 256, 0, stream>>>(cw1, qw2, cmask, cw3, cT, qb, Tpart, lpart);
  k1r<<<dim3(4, 64), 256, 0, stream>>>(Tpart, lpart, TT);
  k2<<<dim3(16, 64), 256, 0, stream>>>(c, cw1, qw2, qmask, cw3, qb, qT, TT, out);
}